// Round 6
// baseline (119.288 us; speedup 1.0000x reference)
//
#include <hip/hip_runtime.h>
#include <hip/hip_fp16.h>

#define H 1024
#define W 1024
#define NC 12   // channels
#define ND 8    // depth
#define HG 16
#define WG 16

#define XSTRIDE 104   // halfs per x column-group (96 data + 8 pad, bank spread)

struct __align__(8) H4 { __half2 lo, hi; };   // 4 halfs = one ds_read_b64

// One block per (n, y). wy block-uniform: y-interp folded into LDS staging.
// LDS holds the y-lerped grid row in fp16: [x(16)][z(8)][c(12)], x-stride 104
// halfs (52 dwords; 52x mod 32 = 20x spreads bank quads across x-cells).
// Main loop: bilinear (x,z) via packed fp16 lerps, 12 ds_read_b64 per pixel,
// fp32 conversion only at the store. 4 px/thread, float4 coalesced stores.
__global__ __launch_bounds__(256, 4) void slice_kernel(
    const float* __restrict__ grid,
    const float* __restrict__ guide,
    float* __restrict__ out)
{
    const int y   = blockIdx.x;
    const int n   = blockIdx.y;
    const int tid = threadIdx.x;

    // Per-row y interpolation (block-uniform), mirroring the reference math.
    float yn = -1.0f + 2.0f * (float)y / (float)(H - 1);
    float iy = (yn + 1.0f) * 0.5f * (float)(HG - 1);
    iy = fminf(fmaxf(iy, 0.0f), (float)(HG - 1));
    int   iy0 = (int)floorf(iy);
    int   iy1 = min(iy0 + 1, HG - 1);
    float wy  = iy - (float)iy0;

    __shared__ __half sg[WG * XSTRIDE];
    const float* gbase = grid + (size_t)n * NC * ND * HG * WG;
    for (int i = tid; i < WG * ND * NC; i += 256) {
        int x  = i & (WG - 1);
        int zc = i >> 4;
        int z  = zc & (ND - 1);
        int c  = zc >> 3;
        const float* gp = gbase + ((c * ND + z) * HG) * WG + x;
        float r0 = gp[iy0 * WG];
        float r1 = gp[iy1 * WG];
        sg[x * XSTRIDE + z * NC + c] = __float2half(r0 + (r1 - r0) * wy);
    }
    __syncthreads();

    const int xb = tid * 4;                       // 4 consecutive pixels/thread
    const float* gd = guide + ((size_t)n * H + y) * W;
    float*       ob = out + ((size_t)n * NC * H + y) * W;  // + c*H*W + x

    const float4 g4 = *(const float4*)&gd[xb];
    const float gz[4] = {g4.x, g4.y, g4.z, g4.w};

    // Per-pixel corner half-index bases and packed weights.
    int     A00[4], A01[4], A10[4], A11[4];
    __half2 wx2v[4], wz2v[4];

    #pragma unroll
    for (int p = 0; p < 4; ++p) {
        const int x = xb + p;
        float xn = -1.0f + 2.0f * (float)x / (float)(W - 1);
        float ix = (xn + 1.0f) * 0.5f * (float)(WG - 1);
        ix = fminf(fmaxf(ix, 0.0f), (float)(WG - 1));
        int   ix0 = (int)floorf(ix);
        int   ix1 = min(ix0 + 1, WG - 1);
        wx2v[p] = __float2half2_rn(ix - (float)ix0);

        float zn = gz[p] * 2.0f - 1.0f;
        float iz = (zn + 1.0f) * 0.5f * (float)(ND - 1);
        iz = fminf(fmaxf(iz, 0.0f), (float)(ND - 1));
        int   iz0 = (int)floorf(iz);
        int   iz1 = min(iz0 + 1, ND - 1);
        wz2v[p] = __float2half2_rn(iz - (float)iz0);

        const int B0 = ix0 * XSTRIDE;
        const int B1 = ix1 * XSTRIDE;
        const int Z0 = iz0 * NC;
        const int Z1 = iz1 * NC;
        A00[p] = B0 + Z0;  A01[p] = B0 + Z1;
        A10[p] = B1 + Z0;  A11[p] = B1 + Z1;
    }

    #pragma unroll
    for (int cc = 0; cc < NC; cc += 4) {
        float4 q[4];   // q[p] = channels cc..cc+3 for pixel p
        #pragma unroll
        for (int p = 0; p < 4; ++p) {
            const __half2 wz2 = wz2v[p], wx2 = wx2v[p];
            const H4 a0 = *(const H4*)&sg[A00[p] + cc];
            const H4 a1 = *(const H4*)&sg[A01[p] + cc];
            const H4 b0 = *(const H4*)&sg[A10[p] + cc];
            const H4 b1 = *(const H4*)&sg[A11[p] + cc];

            // z-lerp then x-lerp, packed over channel pairs
            __half2 zal = __hfma2(__hsub2(a1.lo, a0.lo), wz2, a0.lo);
            __half2 zah = __hfma2(__hsub2(a1.hi, a0.hi), wz2, a0.hi);
            __half2 zbl = __hfma2(__hsub2(b1.lo, b0.lo), wz2, b0.lo);
            __half2 zbh = __hfma2(__hsub2(b1.hi, b0.hi), wz2, b0.hi);
            __half2 rl  = __hfma2(__hsub2(zbl, zal), wx2, zal);
            __half2 rh  = __hfma2(__hsub2(zbh, zah), wx2, zah);

            q[p] = make_float4(__low2float(rl), __high2float(rl),
                               __low2float(rh), __high2float(rh));
        }
        {
            float4 v;
            v = make_float4(q[0].x, q[1].x, q[2].x, q[3].x);
            *(float4*)&ob[(size_t)(cc + 0) * H * W + xb] = v;
            v = make_float4(q[0].y, q[1].y, q[2].y, q[3].y);
            *(float4*)&ob[(size_t)(cc + 1) * H * W + xb] = v;
            v = make_float4(q[0].z, q[1].z, q[2].z, q[3].z);
            *(float4*)&ob[(size_t)(cc + 2) * H * W + xb] = v;
            v = make_float4(q[0].w, q[1].w, q[2].w, q[3].w);
            *(float4*)&ob[(size_t)(cc + 3) * H * W + xb] = v;
        }
    }
}

extern "C" void kernel_launch(void* const* d_in, const int* in_sizes, int n_in,
                              void* d_out, int out_size, void* d_ws, size_t ws_size,
                              hipStream_t stream) {
    const float* grid  = (const float*)d_in[0];
    const float* guide = (const float*)d_in[1];
    float* out = (float*)d_out;

    dim3 grd(H, 2);   // (y, n)
    dim3 blk(256);
    slice_kernel<<<grd, blk, 0, stream>>>(grid, guide, out);
}